// Round 2
// baseline (332.950 us; speedup 1.0000x reference)
//
#include <hip/hip_runtime.h>

#define N_DRUG 20000
#define N_PROT 8000
#define D_DRUG 300
#define D_PROT 1280
#define HIDDEN 512
#define OUT_D  5
#define N_EDGE 500000
#define N_LBL  200000
#define W_LIN_LD (D_DRUG + HIDDEN)   // 812

// --- K1: tiny folded weight matrices -------------------------------------
// A[o,k] = sum_h W_lin[o,300+h] * W_l[h,k]   (5 x 300)
// B[o,k] = sum_h W_lin[o,300+h] * W_r[h,k]   (5 x 1280)
// c[o]   = sum_h W_lin[o,300+h] * b_l[h]     (5)
__global__ void k_small(const float* __restrict__ W_l, const float* __restrict__ W_r,
                        const float* __restrict__ W_lin, const float* __restrict__ b_l,
                        float* __restrict__ A, float* __restrict__ B, float* __restrict__ c) {
    int t = blockIdx.x * blockDim.x + threadIdx.x;
    const int nA = OUT_D * D_DRUG;   // 1500
    const int nB = OUT_D * D_PROT;   // 6400
    if (t < nA) {
        int o = t / D_DRUG, k = t - o * D_DRUG;
        const float* wp = W_lin + o * W_LIN_LD + D_DRUG;
        float s = 0.f;
        for (int h = 0; h < HIDDEN; ++h) s += wp[h] * W_l[h * D_DRUG + k];
        A[t] = s;
    } else if (t < nA + nB) {
        int u = t - nA;
        int o = u / D_PROT, k = u - o * D_PROT;
        const float* wp = W_lin + o * W_LIN_LD + D_DRUG;
        float s = 0.f;
        for (int h = 0; h < HIDDEN; ++h) s += wp[h] * W_r[h * D_PROT + k];
        B[u] = s;
    } else if (t < nA + nB + OUT_D) {
        int o = t - nA - nB;
        const float* wp = W_lin + o * W_LIN_LD + D_DRUG;
        float s = 0.f;
        for (int h = 0; h < HIDDEN; ++h) s += wp[h] * b_l[h];
        c[o] = s;
    }
}

// --- K2: per-drug-row projections: P_A = x_drug @ A.T, drugO = x_drug @ Wlin_d.T
// one wave (64 lanes) per drug row; float4 loads; butterfly reduce.
__global__ void k_drug(const float* __restrict__ x_drug, const float* __restrict__ A,
                       const float* __restrict__ W_lin,
                       float* __restrict__ P_A, float* __restrict__ drugO) {
    int wave = (blockIdx.x * blockDim.x + threadIdx.x) >> 6;
    int lane = threadIdx.x & 63;
    if (wave >= N_DRUG) return;
    const float4* xr = (const float4*)(x_drug + (size_t)wave * D_DRUG);  // 75 float4
    float acc[10];
#pragma unroll
    for (int i = 0; i < 10; ++i) acc[i] = 0.f;
    for (int k = lane; k < D_DRUG / 4; k += 64) {
        float4 x = xr[k];
#pragma unroll
        for (int o = 0; o < OUT_D; ++o) {
            float4 a = ((const float4*)(A + o * D_DRUG))[k];
            acc[o] += x.x * a.x + x.y * a.y + x.z * a.z + x.w * a.w;
            float4 w = ((const float4*)(W_lin + o * W_LIN_LD))[k];
            acc[5 + o] += x.x * w.x + x.y * w.y + x.z * w.z + x.w * w.w;
        }
    }
#pragma unroll
    for (int i = 0; i < 10; ++i) {
        float v = acc[i];
        for (int off = 32; off; off >>= 1) v += __shfl_xor(v, off, 64);
        acc[i] = v;
    }
    if (lane < OUT_D) {
        P_A[wave * OUT_D + lane]   = acc[lane];
        drugO[wave * OUT_D + lane] = acc[5 + lane];
    }
}

// --- K3: 5-wide scatter + degree histogram -------------------------------
__global__ void k_scatter(const int* __restrict__ edge_src, const int* __restrict__ edge_dst,
                          const float* __restrict__ P_A,
                          float* __restrict__ agg5, int* __restrict__ cnt) {
    int e = blockIdx.x * blockDim.x + threadIdx.x;
    if (e >= N_EDGE) return;
    int s = edge_src[e], d = edge_dst[e];
    // hoist loads so they can issue as one dwordx4 + dword before the atomics
    float p0 = P_A[s * OUT_D + 0], p1 = P_A[s * OUT_D + 1], p2 = P_A[s * OUT_D + 2];
    float p3 = P_A[s * OUT_D + 3], p4 = P_A[s * OUT_D + 4];
    atomicAdd(&cnt[d], 1);
    float* ag = &agg5[d * OUT_D];
    atomicAdd(ag + 0, p0);
    atomicAdd(ag + 1, p1);
    atomicAdd(ag + 2, p2);
    atomicAdd(ag + 3, p3);
    atomicAdd(ag + 4, p4);
}

// --- K4: protO = agg5/clip(cnt,1) + x_prot @ B.T + c ---------------------
// one wave per protein row; float4 loads of x_prot (the big 41 MB read).
__global__ void k_prot(const float* __restrict__ x_prot, const float* __restrict__ B,
                       const float* __restrict__ c, const float* __restrict__ agg5,
                       const int* __restrict__ cnt, float* __restrict__ protO) {
    int wave = (blockIdx.x * blockDim.x + threadIdx.x) >> 6;
    int lane = threadIdx.x & 63;
    if (wave >= N_PROT) return;
    const float4* xr = (const float4*)(x_prot + (size_t)wave * D_PROT);  // 320 float4
    float acc[OUT_D] = {0.f, 0.f, 0.f, 0.f, 0.f};
    for (int k = lane; k < D_PROT / 4; k += 64) {
        float4 x = xr[k];
#pragma unroll
        for (int o = 0; o < OUT_D; ++o) {
            float4 b = ((const float4*)(B + o * D_PROT))[k];
            acc[o] += x.x * b.x + x.y * b.y + x.z * b.z + x.w * b.w;
        }
    }
#pragma unroll
    for (int o = 0; o < OUT_D; ++o) {
        float v = acc[o];
        for (int off = 32; off; off >>= 1) v += __shfl_xor(v, off, 64);
        acc[o] = v;
    }
    if (lane < OUT_D) {
        float invc = 1.f / fmaxf((float)cnt[wave], 1.f);
        protO[wave * OUT_D + lane] = agg5[wave * OUT_D + lane] * invc + acc[lane] + c[lane];
    }
}

// --- K5: final gather-add, vectorized 16B+4B store -----------------------
__global__ void k_final(const int* __restrict__ lbl_src, const int* __restrict__ lbl_dst,
                        const float* __restrict__ drugO, const float* __restrict__ protO,
                        const float* __restrict__ b_lin, float* __restrict__ out) {
    int l = blockIdx.x * blockDim.x + threadIdx.x;
    if (l >= N_LBL) return;
    int s = lbl_src[l], d = lbl_dst[l];
    const float* dr = &drugO[s * OUT_D];
    const float* pr = &protO[d * OUT_D];
    float r0 = dr[0] + pr[0] + b_lin[0];
    float r1 = dr[1] + pr[1] + b_lin[1];
    float r2 = dr[2] + pr[2] + b_lin[2];
    float r3 = dr[3] + pr[3] + b_lin[3];
    float r4 = dr[4] + pr[4] + b_lin[4];
    float* op = &out[(size_t)l * OUT_D];
    // rows are 20 B; 16B chunk is only 4B-aligned, so store as 4 dwords + 1
    op[0] = r0; op[1] = r1; op[2] = r2; op[3] = r3; op[4] = r4;
}

extern "C" void kernel_launch(void* const* d_in, const int* in_sizes, int n_in,
                              void* d_out, int out_size, void* d_ws, size_t ws_size,
                              hipStream_t stream) {
    const float* x_drug   = (const float*)d_in[0];
    const float* x_prot   = (const float*)d_in[1];
    const int*   edge_src = (const int*)d_in[2];
    const int*   edge_dst = (const int*)d_in[3];
    const int*   lbl_src  = (const int*)d_in[4];
    const int*   lbl_dst  = (const int*)d_in[5];
    const float* W_l      = (const float*)d_in[6];
    const float* b_l      = (const float*)d_in[7];
    const float* W_r      = (const float*)d_in[8];
    const float* W_lin    = (const float*)d_in[9];
    const float* b_lin    = (const float*)d_in[10];
    float* out = (float*)d_out;

    // workspace layout (all 16B-aligned offsets)
    char* ws = (char*)d_ws;
    int*   cnt   = (int*)  (ws + 0);          //  32000 B (8000 int)
    float* agg5  = (float*)(ws + 32000);      // 160000 B (40000 f)
    float* P_A   = (float*)(ws + 192000);     // 400000 B (100000 f)
    float* drugO = (float*)(ws + 592000);     // 400000 B
    float* protO = (float*)(ws + 992000);     // 160000 B
    float* A     = (float*)(ws + 1152000);    //   6000 B (5x300)
    float* B     = (float*)(ws + 1158000);    //  25600 B (5x1280)
    float* c     = (float*)(ws + 1183600);    //     20 B

    // zero cnt + agg5 (ws is re-poisoned to 0xAA before every launch)
    hipMemsetAsync(ws, 0, 192000, stream);

    k_small<<<(OUT_D * (D_DRUG + D_PROT) + OUT_D + 255) / 256, 256, 0, stream>>>(
        W_l, W_r, W_lin, b_l, A, B, c);
    k_drug<<<(N_DRUG + 3) / 4, 256, 0, stream>>>(x_drug, A, W_lin, P_A, drugO);
    k_scatter<<<(N_EDGE + 255) / 256, 256, 0, stream>>>(edge_src, edge_dst, P_A, agg5, cnt);
    k_prot<<<(N_PROT + 3) / 4, 256, 0, stream>>>(x_prot, B, c, agg5, cnt, protO);
    k_final<<<(N_LBL + 255) / 256, 256, 0, stream>>>(lbl_src, lbl_dst, drugO, protO, b_lin, out);
}

// Round 4
// 176.345 us; speedup vs baseline: 1.8881x; 1.8881x over previous
//
#include <hip/hip_runtime.h>

#define N_DRUG 20000
#define N_PROT 8000
#define D_DRUG 300
#define D_PROT 1280
#define HIDDEN 512
#define OUT_D  5
#define N_EDGE 500000
#define N_LBL  200000
#define W_LIN_LD (D_DRUG + HIDDEN)   // 812
#define CAP    96                    // bucket capacity per protein (deg ~ 62.5 +- 7.9)

// --- K1: tiny folded weights, h-split 8 ways with atomic partial sums ----
// A[o,k] = sum_h W_lin[o,300+h] * W_l[h,k]   (5 x 300)
// B[o,k] = sum_h W_lin[o,300+h] * W_r[h,k]   (5 x 1280)
// c[o]   = sum_h W_lin[o,300+h] * b_l[h]     (5)
// grid.y = 8 chunks of 64 h each; A/B/c zeroed by memset; partials atomicAdd'd.
__global__ void k_small(const float* __restrict__ W_l, const float* __restrict__ W_r,
                        const float* __restrict__ W_lin, const float* __restrict__ b_l,
                        float* __restrict__ A, float* __restrict__ B, float* __restrict__ c) {
    int t = blockIdx.x * blockDim.x + threadIdx.x;
    int h0 = blockIdx.y * 64;
    const int nA = OUT_D * D_DRUG;   // 1500
    const int nB = OUT_D * D_PROT;   // 6400
    if (t < nA) {
        int o = t / D_DRUG, k = t - o * D_DRUG;
        const float* wp = W_lin + o * W_LIN_LD + D_DRUG + h0;
        const float* wl = W_l + (size_t)h0 * D_DRUG + k;
        float s = 0.f;
#pragma unroll 4
        for (int h = 0; h < 64; ++h) s += wp[h] * wl[h * D_DRUG];
        atomicAdd(&A[t], s);
    } else if (t < nA + nB) {
        int u = t - nA;
        int o = u / D_PROT, k = u - o * D_PROT;
        const float* wp = W_lin + o * W_LIN_LD + D_DRUG + h0;
        const float* wr = W_r + (size_t)h0 * D_PROT + k;
        float s = 0.f;
#pragma unroll 4
        for (int h = 0; h < 64; ++h) s += wp[h] * wr[h * D_PROT];
        atomicAdd(&B[u], s);
    } else if (t < nA + nB + OUT_D) {
        int o = t - nA - nB;
        const float* wp = W_lin + o * W_LIN_LD + D_DRUG + h0;
        float s = 0.f;
        for (int h = 0; h < 64; ++h) s += wp[h] * b_l[h0 + h];
        atomicAdd(&c[o], s);
    }
}

// --- K2: P_A = x_drug @ A.T, drugO = x_drug @ Wlin_d.T -------------------
// 16 lanes per drug row (4 rows/wave): 75 float4 -> 5 near-full iterations.
__global__ void k_drug(const float* __restrict__ x_drug, const float* __restrict__ A,
                       const float* __restrict__ W_lin,
                       float* __restrict__ P_A, float* __restrict__ drugO) {
    int gid = blockIdx.x * blockDim.x + threadIdx.x;
    int row = gid >> 4;
    int sub = threadIdx.x & 15;
    if (row >= N_DRUG) return;
    const float4* xr = (const float4*)(x_drug + (size_t)row * D_DRUG);  // 75 float4
    float acc[10];
#pragma unroll
    for (int i = 0; i < 10; ++i) acc[i] = 0.f;
    for (int k = sub; k < D_DRUG / 4; k += 16) {
        float4 x = xr[k];
#pragma unroll
        for (int o = 0; o < OUT_D; ++o) {
            float4 a = ((const float4*)(A + o * D_DRUG))[k];
            acc[o] += x.x * a.x + x.y * a.y + x.z * a.z + x.w * a.w;
            float4 w = ((const float4*)(W_lin + o * W_LIN_LD))[k];
            acc[5 + o] += x.x * w.x + x.y * w.y + x.z * w.z + x.w * w.w;
        }
    }
    // reduce within 16-lane group (xor 1..8 stays inside the group)
#pragma unroll
    for (int i = 0; i < 10; ++i) {
        float v = acc[i];
        for (int m = 8; m; m >>= 1) v += __shfl_xor(v, m, 64);
        acc[i] = v;
    }
    if (sub < OUT_D) {
        P_A[row * OUT_D + sub]   = acc[sub];
        drugO[row * OUT_D + sub] = acc[5 + sub];
    }
}

// --- K3: bucketed index scatter ------------------------------------------
// r = cnt[d]++; bucket[d*CAP+r] = s. Overflow (r>=CAP, ~4-sigma tail) falls
// back to direct atomic accumulation into agg5 — exact, just slow, ~never hit.
__global__ void k_place(const int* __restrict__ edge_src, const int* __restrict__ edge_dst,
                        const float* __restrict__ P_A,
                        int* __restrict__ bucket, int* __restrict__ cnt,
                        float* __restrict__ agg5) {
    int e = blockIdx.x * blockDim.x + threadIdx.x;
    if (e >= N_EDGE) return;
    int s = edge_src[e], d = edge_dst[e];
    int r = atomicAdd(&cnt[d], 1);
    if (r < CAP) {
        bucket[(size_t)d * CAP + r] = s;
    } else {
        const float* p = &P_A[s * OUT_D];
#pragma unroll
        for (int o = 0; o < OUT_D; ++o) atomicAdd(&agg5[d * OUT_D + o], p[o]);
    }
}

// --- K4: protO = (gather-sum + agg5)/clip(cnt,1) + x_prot @ B.T + c ------
// one wave per protein row; float4 x_prot loads + bucket gather of P_A rows.
__global__ void k_prot(const float* __restrict__ x_prot, const float* __restrict__ B,
                       const float* __restrict__ c, const float* __restrict__ agg5,
                       const int* __restrict__ cnt, const int* __restrict__ bucket,
                       const float* __restrict__ P_A, float* __restrict__ protO) {
    int wave = (blockIdx.x * blockDim.x + threadIdx.x) >> 6;
    int lane = threadIdx.x & 63;
    if (wave >= N_PROT) return;
    const float4* xr = (const float4*)(x_prot + (size_t)wave * D_PROT);  // 320 float4
    float acc[10];
#pragma unroll
    for (int i = 0; i < 10; ++i) acc[i] = 0.f;
    for (int k = lane; k < D_PROT / 4; k += 64) {
        float4 x = xr[k];
#pragma unroll
        for (int o = 0; o < OUT_D; ++o) {
            float4 b = ((const float4*)(B + o * D_PROT))[k];
            acc[o] += x.x * b.x + x.y * b.y + x.z * b.z + x.w * b.w;
        }
    }
    int deg = cnt[wave];
    int m = deg < CAP ? deg : CAP;
    const int* br = &bucket[(size_t)wave * CAP];
    for (int j = lane; j < m; j += 64) {
        const float* p = &P_A[br[j] * OUT_D];
#pragma unroll
        for (int o = 0; o < OUT_D; ++o) acc[5 + o] += p[o];
    }
#pragma unroll
    for (int i = 0; i < 10; ++i) {
        float v = acc[i];
        for (int off = 32; off; off >>= 1) v += __shfl_xor(v, off, 64);
        acc[i] = v;
    }
    if (lane < OUT_D) {
        float invc = 1.f / fmaxf((float)deg, 1.f);
        protO[wave * OUT_D + lane] =
            (acc[5 + lane] + agg5[wave * OUT_D + lane]) * invc + acc[lane] + c[lane];
    }
}

// --- K5: final gather-add ------------------------------------------------
__global__ void k_final(const int* __restrict__ lbl_src, const int* __restrict__ lbl_dst,
                        const float* __restrict__ drugO, const float* __restrict__ protO,
                        const float* __restrict__ b_lin, float* __restrict__ out) {
    int l = blockIdx.x * blockDim.x + threadIdx.x;
    if (l >= N_LBL) return;
    int s = lbl_src[l], d = lbl_dst[l];
    const float* dr = &drugO[s * OUT_D];
    const float* pr = &protO[d * OUT_D];
    float* op = &out[(size_t)l * OUT_D];
    op[0] = dr[0] + pr[0] + b_lin[0];
    op[1] = dr[1] + pr[1] + b_lin[1];
    op[2] = dr[2] + pr[2] + b_lin[2];
    op[3] = dr[3] + pr[3] + b_lin[3];
    op[4] = dr[4] + pr[4] + b_lin[4];
}

extern "C" void kernel_launch(void* const* d_in, const int* in_sizes, int n_in,
                              void* d_out, int out_size, void* d_ws, size_t ws_size,
                              hipStream_t stream) {
    const float* x_drug   = (const float*)d_in[0];
    const float* x_prot   = (const float*)d_in[1];
    const int*   edge_src = (const int*)d_in[2];
    const int*   edge_dst = (const int*)d_in[3];
    const int*   lbl_src  = (const int*)d_in[4];
    const int*   lbl_dst  = (const int*)d_in[5];
    const float* W_l      = (const float*)d_in[6];
    const float* b_l      = (const float*)d_in[7];
    const float* W_r      = (const float*)d_in[8];
    const float* W_lin    = (const float*)d_in[9];
    const float* b_lin    = (const float*)d_in[10];
    float* out = (float*)d_out;

    // workspace layout (16B-aligned offsets); [0, 224000) is memset to zero
    char* ws = (char*)d_ws;
    int*   cnt    = (int*)  (ws + 0);          //  32000 B (8000 int)      [zeroed]
    float* agg5   = (float*)(ws + 32000);      // 160000 B (40000 f)      [zeroed]
    float* A      = (float*)(ws + 192000);     //   6000 B (5x300)        [zeroed]
    float* B      = (float*)(ws + 198016);     //  25600 B (5x1280)       [zeroed]
    float* c      = (float*)(ws + 223616);     //     20 B                [zeroed]
    float* P_A    = (float*)(ws + 224000);     // 400000 B (100000 f)
    float* drugO  = (float*)(ws + 624000);     // 400000 B
    float* protO  = (float*)(ws + 1024000);    // 160000 B
    int*   bucket = (int*)  (ws + 1184000);    // 3072000 B (8000 x 96 int)
    // total: 4,256,000 B

    hipMemsetAsync(ws, 0, 224000, stream);

    dim3 gs((OUT_D * (D_DRUG + D_PROT) + OUT_D + 255) / 256, HIDDEN / 64);  // (31, 8)
    k_small<<<gs, 256, 0, stream>>>(W_l, W_r, W_lin, b_l, A, B, c);
    k_drug<<<(N_DRUG * 16 + 255) / 256, 256, 0, stream>>>(x_drug, A, W_lin, P_A, drugO);
    k_place<<<(N_EDGE + 255) / 256, 256, 0, stream>>>(edge_src, edge_dst, P_A, bucket, cnt, agg5);
    k_prot<<<(N_PROT * 64 + 255) / 256, 256, 0, stream>>>(x_prot, B, c, agg5, cnt, bucket, P_A, protO);
    k_final<<<(N_LBL + 255) / 256, 256, 0, stream>>>(lbl_src, lbl_dst, drugO, protO, b_lin, out);
}

// Round 6
// 164.964 us; speedup vs baseline: 2.0183x; 1.0690x over previous
//
#include <hip/hip_runtime.h>

#define N_DRUG 20000
#define N_PROT 8000
#define D_DRUG 300
#define D_PROT 1280
#define HIDDEN 512
#define OUT_D  5
#define N_EDGE 500000
#define N_LBL  200000
#define WLD    812        // W_lin leading dim (300+512)
#define CAP    128        // bucket capacity (deg ~ 62.5 +- 7.9; 128 ~ 8 sigma)
#define OVF_MAX 65536     // exact overflow list capacity (never expected to fill)

// =========================================================================
// D1: input-only work fused in one dispatch via block specialization:
//   blocks [0,248):   folded weights A/B/c (h-split 8x, atomic partials)
//   blocks [248,493): bucketed edge scatter (atomic slot reservation)
// The ~21us atomic wall of the scatter hides the weight folding entirely.
// =========================================================================
__global__ void k_stage1(const float* __restrict__ W_l, const float* __restrict__ W_r,
                         const float* __restrict__ W_lin, const float* __restrict__ b_l,
                         const int* __restrict__ edge_src, const int* __restrict__ edge_dst,
                         float* __restrict__ A, float* __restrict__ B, float* __restrict__ c,
                         int* __restrict__ cnt, int* __restrict__ novf,
                         int* __restrict__ bucket, int* __restrict__ ovf) {
    int b = blockIdx.x;
    if (b < 248) {
        // ---- folded weights: A[o,k]=sum_h Wlp[o,h]W_l[h,k] etc. ----
        int t  = (b % 31) * 256 + threadIdx.x;
        int h0 = (b / 31) * 64;
        const int nA = OUT_D * D_DRUG;   // 1500
        const int nB = OUT_D * D_PROT;   // 6400
        if (t < nA) {
            int o = t / D_DRUG, k = t - o * D_DRUG;
            const float* wp = W_lin + o * WLD + D_DRUG + h0;
            const float* wl = W_l + (size_t)h0 * D_DRUG + k;
            float s = 0.f;
#pragma unroll 4
            for (int h = 0; h < 64; ++h) s += wp[h] * wl[h * D_DRUG];
            atomicAdd(&A[t], s);
        } else if (t < nA + nB) {
            int u = t - nA;
            int o = u / D_PROT, k = u - o * D_PROT;
            const float* wp = W_lin + o * WLD + D_DRUG + h0;
            const float* wr = W_r + (size_t)h0 * D_PROT + k;
            float s = 0.f;
#pragma unroll 4
            for (int h = 0; h < 64; ++h) s += wp[h] * wr[h * D_PROT];
            atomicAdd(&B[u], s);
        } else if (t < nA + nB + OUT_D) {
            int o = t - nA - nB;
            const float* wp = W_lin + o * WLD + D_DRUG + h0;
            float s = 0.f;
            for (int h = 0; h < 64; ++h) s += wp[h] * b_l[h0 + h];
            atomicAdd(&c[o], s);
        }
    } else {
        // ---- bucketed scatter: r = cnt[d]++; bucket[d*CAP+r] = s ----
        // overflow (r>=CAP) goes to an exact (d,s) list — input-only.
        int base = (b - 248) * 2048 + threadIdx.x;
#pragma unroll
        for (int i = 0; i < 8; ++i) {
            int e = base + i * 256;
            if (e < N_EDGE) {
                int s = edge_src[e], d = edge_dst[e];
                int r = atomicAdd(&cnt[d], 1);
                if (r < CAP) {
                    bucket[d * CAP + r] = s;
                } else {
                    int o = atomicAdd(novf, 1);
                    if (o < OVF_MAX) { ovf[2 * o] = d; ovf[2 * o + 1] = s; }
                }
            }
        }
    }
}

// =========================================================================
// D2: both dense row-projections fused (L1-bound drug GEMM overlaps the
// HBM-bound x_prot stream):
//   blocks [0,1250):    P_A = x_drug@A.T, drugO = x_drug@Wlin_d.T (16 ln/row)
//   blocks [1250,3250): protO = x_prot@B.T + c                    (64 ln/row)
// =========================================================================
__global__ void k_stage2(const float* __restrict__ x_drug, const float* __restrict__ x_prot,
                         const float* __restrict__ A, const float* __restrict__ B,
                         const float* __restrict__ c, const float* __restrict__ W_lin,
                         float* __restrict__ P_A, float* __restrict__ drugO,
                         float* __restrict__ protO) {
    int b = blockIdx.x;
    if (b < 1250) {
        int gid = b * 256 + threadIdx.x;
        int row = gid >> 4;              // 1250*256/16 = 20000 exactly
        int sub = threadIdx.x & 15;
        const float4* xr = (const float4*)(x_drug + (size_t)row * D_DRUG);  // 75 float4
        float acc[10];
#pragma unroll
        for (int i = 0; i < 10; ++i) acc[i] = 0.f;
        for (int k = sub; k < D_DRUG / 4; k += 16) {
            float4 x = xr[k];
#pragma unroll
            for (int o = 0; o < OUT_D; ++o) {
                float4 a = ((const float4*)(A + o * D_DRUG))[k];
                acc[o] += x.x * a.x + x.y * a.y + x.z * a.z + x.w * a.w;
                float4 w = ((const float4*)(W_lin + o * WLD))[k];
                acc[5 + o] += x.x * w.x + x.y * w.y + x.z * w.z + x.w * w.w;
            }
        }
#pragma unroll
        for (int i = 0; i < 10; ++i) {
            float v = acc[i];
            for (int m = 8; m; m >>= 1) v += __shfl_xor(v, m, 64);
            acc[i] = v;
        }
        if (sub < OUT_D) {
            P_A[row * OUT_D + sub]   = acc[sub];
            drugO[row * OUT_D + sub] = acc[5 + sub];
        }
    } else {
        int wave = ((b - 1250) * 256 + threadIdx.x) >> 6;  // 2000*256/64 = 8000 exactly
        int lane = threadIdx.x & 63;
        const float4* xr = (const float4*)(x_prot + (size_t)wave * D_PROT);  // 320 float4
        float acc[OUT_D] = {0.f, 0.f, 0.f, 0.f, 0.f};
        for (int k = lane; k < D_PROT / 4; k += 64) {
            float4 x = xr[k];
#pragma unroll
            for (int o = 0; o < OUT_D; ++o) {
                float4 bb = ((const float4*)(B + o * D_PROT))[k];
                acc[o] += x.x * bb.x + x.y * bb.y + x.z * bb.z + x.w * bb.w;
            }
        }
#pragma unroll
        for (int o = 0; o < OUT_D; ++o) {
            float v = acc[o];
            for (int off = 32; off; off >>= 1) v += __shfl_xor(v, off, 64);
            acc[o] = v;
        }
        if (lane < OUT_D) protO[wave * OUT_D + lane] = acc[lane] + c[lane];
    }
}

// =========================================================================
// D3: bucket gather-mean, added into protO (one wave per protein)
// grid MUST be N_PROT*64/256 = 2000 blocks (was the round-5 bug: 125)
// =========================================================================
__global__ void k_gather(const int* __restrict__ cnt, const int* __restrict__ novf,
                         const int* __restrict__ bucket, const int* __restrict__ ovf,
                         const float* __restrict__ P_A, float* __restrict__ protO) {
    int wave = (blockIdx.x * blockDim.x + threadIdx.x) >> 6;
    int lane = threadIdx.x & 63;
    if (wave >= N_PROT) return;
    int deg = cnt[wave];
    int m = deg < CAP ? deg : CAP;
    float acc[OUT_D] = {0.f, 0.f, 0.f, 0.f, 0.f};
    const int* br = &bucket[wave * CAP];
    for (int j = lane; j < m; j += 64) {
        const float* p = &P_A[br[j] * OUT_D];
#pragma unroll
        for (int o = 0; o < OUT_D; ++o) acc[o] += p[o];
    }
    if (deg > CAP) {   // exact tail: scan the tiny overflow list
        int nv = *novf; if (nv > OVF_MAX) nv = OVF_MAX;
        for (int j = lane; j < nv; j += 64) {
            if (ovf[2 * j] == wave) {
                const float* p = &P_A[ovf[2 * j + 1] * OUT_D];
#pragma unroll
                for (int o = 0; o < OUT_D; ++o) acc[o] += p[o];
            }
        }
    }
#pragma unroll
    for (int o = 0; o < OUT_D; ++o) {
        float v = acc[o];
        for (int off = 32; off; off >>= 1) v += __shfl_xor(v, off, 64);
        acc[o] = v;
    }
    if (lane < OUT_D)
        protO[wave * OUT_D + lane] += acc[lane] / fmaxf((float)deg, 1.f);
}

// =========================================================================
// D4: final gather-add
// =========================================================================
__global__ void k_final(const int* __restrict__ lbl_src, const int* __restrict__ lbl_dst,
                        const float* __restrict__ drugO, const float* __restrict__ protO,
                        const float* __restrict__ b_lin, float* __restrict__ out) {
    int l = blockIdx.x * blockDim.x + threadIdx.x;
    if (l >= N_LBL) return;
    int s = lbl_src[l], d = lbl_dst[l];
    const float* dr = &drugO[s * OUT_D];
    const float* pr = &protO[d * OUT_D];
    float* op = &out[(size_t)l * OUT_D];
    op[0] = dr[0] + pr[0] + b_lin[0];
    op[1] = dr[1] + pr[1] + b_lin[1];
    op[2] = dr[2] + pr[2] + b_lin[2];
    op[3] = dr[3] + pr[3] + b_lin[3];
    op[4] = dr[4] + pr[4] + b_lin[4];
}

extern "C" void kernel_launch(void* const* d_in, const int* in_sizes, int n_in,
                              void* d_out, int out_size, void* d_ws, size_t ws_size,
                              hipStream_t stream) {
    const float* x_drug   = (const float*)d_in[0];
    const float* x_prot   = (const float*)d_in[1];
    const int*   edge_src = (const int*)d_in[2];
    const int*   edge_dst = (const int*)d_in[3];
    const int*   lbl_src  = (const int*)d_in[4];
    const int*   lbl_dst  = (const int*)d_in[5];
    const float* W_l      = (const float*)d_in[6];
    const float* b_l      = (const float*)d_in[7];
    const float* W_r      = (const float*)d_in[8];
    const float* W_lin    = (const float*)d_in[9];
    const float* b_lin    = (const float*)d_in[10];
    float* out = (float*)d_out;

    // workspace layout; [0, 63648) zeroed by the single memset
    char* ws = (char*)d_ws;
    int*   cnt    = (int*)  (ws + 0);          //  32000 B (8000)      [zeroed]
    int*   novf   = (int*)  (ws + 32000);      //     16 B            [zeroed]
    float* A      = (float*)(ws + 32016);      //   6000 B (5x300)    [zeroed]
    float* B      = (float*)(ws + 38016);      //  25600 B (5x1280)   [zeroed]
    float* c      = (float*)(ws + 63616);      //     20 B            [zeroed]
    float* P_A    = (float*)(ws + 64000);      // 400000 B
    float* drugO  = (float*)(ws + 464000);     // 400000 B
    float* protO  = (float*)(ws + 864000);     // 160000 B
    int*   bucket = (int*)  (ws + 1024000);    // 4096000 B (8000 x 128)
    int*   ovf    = (int*)  (ws + 5120000);    // 524288 B (65536 pairs)
    // total: 5,644,288 B

    hipMemsetAsync(ws, 0, 63648, stream);
    k_stage1<<<493, 256, 0, stream>>>(W_l, W_r, W_lin, b_l, edge_src, edge_dst,
                                      A, B, c, cnt, novf, bucket, ovf);
    k_stage2<<<3250, 256, 0, stream>>>(x_drug, x_prot, A, B, c, W_lin,
                                       P_A, drugO, protO);
    k_gather<<<(N_PROT * 64) / 256, 256, 0, stream>>>(cnt, novf, bucket, ovf, P_A, protO);
    k_final<<<(N_LBL + 255) / 256, 256, 0, stream>>>(lbl_src, lbl_dst, drugO, protO, b_lin, out);
}